// Round 2
// baseline (211.568 us; speedup 1.0000x reference)
//
#include <hip/hip_runtime.h>
#include <hip/hip_bf16.h>

// Problem constants: b=8, lq=lk=2048, d=256
#define BB 8
#define LQ 2048
#define LK 2048
#define DD 256
#define OUT0_N (BB*LQ*DD)      // 4194304 elements (LN output), attn follows

typedef short s16x8 __attribute__((ext_vector_type(8)));
typedef float f32x4 __attribute__((ext_vector_type(4)));

__device__ __forceinline__ unsigned short f2b(float x){
  unsigned int u = __float_as_uint(x);
  u += 0x7fffu + ((u >> 16) & 1u);           // RNE
  return (unsigned short)(u >> 16);
}
__device__ __forceinline__ float b2f(unsigned short h){
  return __uint_as_float(((unsigned int)h) << 16);
}
__device__ __forceinline__ float ldf(const void* p, long i, int bf){
  return bf ? b2f(((const unsigned short*)p)[i]) : ((const float*)p)[i];
}
__device__ __forceinline__ s16x8 ld8(const void* p, long i, int bf){
  if (bf) return *(const s16x8*)((const unsigned short*)p + i);
  const float* f = (const float*)p + i;
  float4 a = *(const float4*)(f);
  float4 c = *(const float4*)(f + 4);
  s16x8 r;
  r[0]=(short)f2b(a.x); r[1]=(short)f2b(a.y); r[2]=(short)f2b(a.z); r[3]=(short)f2b(a.w);
  r[4]=(short)f2b(c.x); r[5]=(short)f2b(c.y); r[6]=(short)f2b(c.z); r[7]=(short)f2b(c.w);
  return r;
}
__device__ __forceinline__ float wsum(float v){
  #pragma unroll
  for (int o=32;o;o>>=1) v += __shfl_xor(v, o, 64);
  return v;
}

// ---------------- K0: runtime dtype detection ----------------
__global__ void k_detect(const void* q, const void* mask, int* flags){
  __shared__ int sb, sc;
  if (threadIdx.x == 0){ sb = 0; sc = 0; }
  __syncthreads();
  const unsigned int* mw = (const unsigned int*)mask;
  int any = 0;
  for (int i = threadIdx.x; i < 1024; i += 256) if (mw[i] > 1u) any = 1;
  if (any) atomicOr(&sb, 1);
  float x = fabsf(((const float*)q)[threadIdx.x]);
  if (x > 1e-6f && x < 100.0f) atomicAdd(&sc, 1);
  __syncthreads();
  if (threadIdx.x == 0){
    flags[0] = sb;
    flags[1] = (sc < 192) ? 1 : 0;
  }
}

// ---------------- K1: e[b,j] = exp(dot(k[b,j,:], w_k)) ----------------
__global__ __launch_bounds__(256) void k_sk(const void* kk, const void* sh,
                                            float* e, const int* flags){
  int bf = flags[1];
  int wid  = (blockIdx.x << 2) + (threadIdx.x >> 6);   // row 0..16383
  int lane = threadIdx.x & 63;
  long base = (long)wid * DD + lane * 4;
  float acc = 0.f;
  #pragma unroll
  for (int c = 0; c < 4; ++c)
    acc += ldf(kk, base + c, bf) * ldf(sh, DD + lane*4 + c, bf);
  acc = wsum(acc);
  if (lane == 0) e[wid] = __expf(acc);
}

// ---------------- K1b: vt[b][d][j] = sum_e fc_w[d][e] * v[b,j,e]  (bf16) ----------------
__global__ __launch_bounds__(256) void k_vt(const void* v, const void* fc,
                                            unsigned short* vt, const int* flags){
  int bf = flags[1];
  int wid  = (blockIdx.x << 2) + (threadIdx.x >> 6);   // 0..4095
  int lane = threadIdx.x & 63;
  int dbase = (wid & 15) << 4;
  int jbase = (wid >> 4) << 6;
  int r = lane & 15, g = lane >> 4;
  f32x4 acc[4];
  #pragma unroll
  for (int t2=0;t2<4;t2++) acc[t2] = (f32x4){0.f,0.f,0.f,0.f};
  #pragma unroll
  for (int ks = 0; ks < 8; ++ks){
    int k0 = ks*32 + g*8;
    s16x8 a = ld8(fc, (long)(dbase + r)*DD + k0, bf);
    #pragma unroll
    for (int t2 = 0; t2 < 4; ++t2){
      s16x8 bq = ld8(v, (long)(jbase + t2*16 + r)*DD + k0, bf);
      acc[t2] = __builtin_amdgcn_mfma_f32_16x16x32_bf16(a, bq, acc[t2], 0, 0, 0);
    }
  }
  int bidx = jbase >> 11;
  int jj   = jbase & 2047;
  long vb  = (long)bidx * DD * LK;
  #pragma unroll
  for (int t2 = 0; t2 < 4; ++t2){
    #pragma unroll
    for (int reg = 0; reg < 4; ++reg){
      int d = dbase + g*4 + reg;
      int j = jj + t2*16 + r;
      vt[vb + (long)d*LK + j] = f2b(acc[t2][reg]);
    }
  }
}

// ---------------- K2: per-row softmax denominator: scale[i] = 1/E_i (or -1 if all masked) ----------------
__global__ __launch_bounds__(256) void k_rowstat(const void* mask, const float* e,
                                                 float* scale, const int* flags){
  int mbytes = flags[0];
  int row  = (blockIdx.x << 2) + (threadIdx.x >> 6);   // 0..16383
  int lane = threadIdx.x & 63;
  int b = row >> 11;
  const float* eb = e + b * LK;
  long rowm = (long)row * LK;
  unsigned long long mw[4];
  if (mbytes){
    const unsigned long long* mp =
      (const unsigned long long*)((const unsigned char*)mask + rowm + lane*32);
    #pragma unroll
    for (int w=0;w<4;++w) mw[w] = mp[w];
  } else {
    const int* ip = (const int*)mask + rowm + lane*32;
    #pragma unroll
    for (int w=0;w<4;++w){
      int4 a = *(const int4*)(ip + w*8);
      int4 c = *(const int4*)(ip + w*8 + 4);
      mw[w] = (unsigned long long)(a.x!=0)        | ((unsigned long long)(a.y!=0)<<8)
            | ((unsigned long long)(a.z!=0)<<16)  | ((unsigned long long)(a.w!=0)<<24)
            | ((unsigned long long)(c.x!=0)<<32)  | ((unsigned long long)(c.y!=0)<<40)
            | ((unsigned long long)(c.z!=0)<<48)  | ((unsigned long long)(c.w!=0)<<56);
    }
  }
  float s = 0.f;
  #pragma unroll
  for (int w = 0; w < 4; ++w){
    float4 e0 = *(const float4*)(eb + lane*32 + w*8);
    float4 e1 = *(const float4*)(eb + lane*32 + w*8 + 4);
    unsigned long long m = mw[w];
    if (!((m      ) & 1ull)) s += e0.x;
    if (!((m >>  8) & 1ull)) s += e0.y;
    if (!((m >> 16) & 1ull)) s += e0.z;
    if (!((m >> 24) & 1ull)) s += e0.w;
    if (!((m >> 32) & 1ull)) s += e1.x;
    if (!((m >> 40) & 1ull)) s += e1.y;
    if (!((m >> 48) & 1ull)) s += e1.z;
    if (!((m >> 56) & 1ull)) s += e1.w;
  }
  s = wsum(s);
  if (lane == 0) scale[row] = (s > 0.f) ? (1.0f / s) : -1.0f;
}

// ---------------- K3: fused p-gen + attn-write + PV GEMM + residual + LN ----------------
// BM=32 rows x 256 cols per block, 256 threads (4 waves, wave tile 32x64), K=2048 in BK=64.
// A (p) generated on the fly into dbuf LDS; B (vt) loaded direct from L2 into regs (dbuf).
__global__ __launch_bounds__(256) void k_pvf(void* d_out, const unsigned short* vt,
    const void* q, const void* gamp, const void* betp,
    const void* mask, const float* e, const float* scale, const int* flags){
  __shared__ unsigned short As[2][32][72];
  __shared__ float psum[4][32], psq[4][32];
  __shared__ float mu_s[32], rs_s[32];
  __shared__ float gs[256], bs[256];
  int mbytes = flags[0], bf = flags[1];
  int b     = blockIdx.x >> 6;
  int rbase = (blockIdx.x & 63) << 5;
  int t = threadIdx.x, lane = t & 63, wid = t >> 6;
  int r16 = lane >> 4, c16 = lane & 15;
  gs[t] = ldf(gamp, t, bf);
  bs[t] = ldf(betp, t, bf);

  // p-gen thread mapping
  int prow = t >> 3, part = t & 7;
  long rowg = (long)b*LQ + rbase + prow;
  long rowm = rowg * (long)LK;
  float scal = scale[rowg];
  const float* eb = e + b * LK;
  unsigned short* attn16 = (unsigned short*)d_out + OUT0_N;
  float*          attn32 = (float*)d_out + OUT0_N;
  const unsigned short* vtb = vt + (long)b * DD * LK;

  f32x4 acc[2][4];
  #pragma unroll
  for (int i=0;i<2;i++)
    #pragma unroll
    for (int j=0;j<4;j++) acc[i][j] = (f32x4){0.f,0.f,0.f,0.f};
  s16x8 B0[8], B1[8];

  auto BLOAD = [&](int tt, s16x8* Bv){
    int k0 = tt << 6;
    #pragma unroll
    for (int ni = 0; ni < 4; ++ni){
      long cb = (long)(wid*64 + ni*16 + c16) * LK + k0 + r16*8;
      Bv[ni*2+0] = *(const s16x8*)(vtb + cb);
      Bv[ni*2+1] = *(const s16x8*)(vtb + cb + 32);
    }
  };
  auto PGEN = [&](int tt, int buf){
    int j0 = (tt << 6) + part*8;
    unsigned long long m8;
    if (mbytes){
      m8 = *(const unsigned long long*)((const unsigned char*)mask + rowm + j0);
    } else {
      const int* ip = (const int*)mask + rowm + j0;
      int4 a = *(const int4*)ip, c = *(const int4*)(ip + 4);
      m8 = (unsigned long long)(a.x!=0)        | ((unsigned long long)(a.y!=0)<<8)
         | ((unsigned long long)(a.z!=0)<<16)  | ((unsigned long long)(a.w!=0)<<24)
         | ((unsigned long long)(c.x!=0)<<32)  | ((unsigned long long)(c.y!=0)<<40)
         | ((unsigned long long)(c.z!=0)<<48)  | ((unsigned long long)(c.w!=0)<<56);
    }
    float4 e0 = *(const float4*)(eb + j0);
    float4 e1 = *(const float4*)(eb + j0 + 4);
    float p[8] = {e0.x,e0.y,e0.z,e0.w,e1.x,e1.y,e1.z,e1.w};
    s16x8 w;
    #pragma unroll
    for (int c = 0; c < 8; ++c){
      float pv = (scal < 0.f) ? (1.0f/2048.0f)
               : ((((m8 >> (8*c)) & 1ull) != 0ull) ? 0.f : p[c]*scal);
      p[c] = pv;
      w[c] = (short)f2b(pv);
    }
    *(s16x8*)(&As[buf][prow][part*8]) = w;
    if (bf){
      *(s16x8*)(attn16 + rowm + j0) = w;
    } else {
      float4 o0 = {p[0],p[1],p[2],p[3]}, o1 = {p[4],p[5],p[6],p[7]};
      *(float4*)(attn32 + rowm + j0)     = o0;
      *(float4*)(attn32 + rowm + j0 + 4) = o1;
    }
  };
  auto COMPUTE = [&](int buf, s16x8* Bv){
    #pragma unroll
    for (int kg = 0; kg < 2; ++kg){
      int ko = kg*32 + r16*8;
      s16x8 a0 = *(const s16x8*)(&As[buf][c16][ko]);
      s16x8 a1 = *(const s16x8*)(&As[buf][16 + c16][ko]);
      #pragma unroll
      for (int ni = 0; ni < 4; ++ni){
        acc[0][ni] = __builtin_amdgcn_mfma_f32_16x16x32_bf16(a0, Bv[ni*2+kg], acc[0][ni], 0,0,0);
        acc[1][ni] = __builtin_amdgcn_mfma_f32_16x16x32_bf16(a1, Bv[ni*2+kg], acc[1][ni], 0,0,0);
      }
    }
  };

  PGEN(0, 0); BLOAD(0, B0);
  __syncthreads();
  #pragma unroll 1
  for (int tt = 0; tt < 32; tt += 2){
    BLOAD(tt+1, B1); PGEN(tt+1, 1);      // prefetch odd tile
    COMPUTE(0, B0);                       // compute even tile
    __syncthreads();
    if (tt + 2 < 32){ BLOAD(tt+2, B0); PGEN(tt+2, 0); }
    COMPUTE(1, B1);                       // compute odd tile
    __syncthreads();
  }

  // epilogue: residual + LN
  #pragma unroll
  for (int mi = 0; mi < 2; ++mi){
    #pragma unroll
    for (int reg = 0; reg < 4; ++reg){
      int rl = mi*16 + r16*4 + reg;
      long grow = (long)b*LQ + rbase + rl;
      float ps = 0.f, pq = 0.f;
      #pragma unroll
      for (int ni = 0; ni < 4; ++ni){
        int col = wid*64 + ni*16 + c16;
        float x = acc[mi][ni][reg] + ldf(q, grow*(long)DD + col, bf);
        acc[mi][ni][reg] = x;
        ps += x; pq += x*x;
      }
      ps += __shfl_xor(ps, 1, 64); pq += __shfl_xor(pq, 1, 64);
      ps += __shfl_xor(ps, 2, 64); pq += __shfl_xor(pq, 2, 64);
      ps += __shfl_xor(ps, 4, 64); pq += __shfl_xor(pq, 4, 64);
      ps += __shfl_xor(ps, 8, 64); pq += __shfl_xor(pq, 8, 64);
      if (c16 == 0){ psum[wid][rl] = ps; psq[wid][rl] = pq; }
    }
  }
  __syncthreads();
  if (t < 32){
    float s  = psum[0][t] + psum[1][t] + psum[2][t] + psum[3][t];
    float s2 = psq [0][t] + psq [1][t] + psq [2][t] + psq [3][t];
    float mu = s * (1.0f/256.0f);
    float var = s2 * (1.0f/256.0f) - mu*mu;
    mu_s[t] = mu;
    rs_s[t] = rsqrtf(var + 1e-5f);
  }
  __syncthreads();
  #pragma unroll
  for (int mi = 0; mi < 2; ++mi){
    #pragma unroll
    for (int ni = 0; ni < 4; ++ni){
      int col = wid*64 + ni*16 + c16;
      float g = gs[col], be = bs[col];
      #pragma unroll
      for (int reg = 0; reg < 4; ++reg){
        int rl = mi*16 + r16*4 + reg;
        float y = (acc[mi][ni][reg] - mu_s[rl]) * rs_s[rl] * g + be;
        long oi = ((long)b*LQ + rbase + rl)*(long)DD + col;
        if (bf) ((unsigned short*)d_out)[oi] = f2b(y);
        else    ((float*)d_out)[oi] = y;
      }
    }
  }
}

extern "C" void kernel_launch(void* const* d_in, const int* in_sizes, int n_in,
                              void* d_out, int out_size, void* d_ws, size_t ws_size,
                              hipStream_t stream) {
  const void* q    = d_in[0];
  const void* k    = d_in[1];
  const void* v    = d_in[2];
  const void* sh   = d_in[3];
  const void* fc   = d_in[4];
  const void* gam  = d_in[5];
  const void* bet  = d_in[6];
  const void* mask = d_in[7];

  int*            flags = (int*)d_ws;
  float*          e     = (float*)((char*)d_ws + 1024);      // 16384 f32 (64 KB)
  float*          scale = (float*)((char*)d_ws + 66560);     // 16384 f32 (64 KB)
  unsigned short* vt    = (unsigned short*)((char*)d_ws + 262144); // 8 MB bf16

  k_detect <<<1,    256, 0, stream>>>(q, mask, flags);
  k_sk     <<<4096, 256, 0, stream>>>(k, sh, e, flags);
  k_vt     <<<1024, 256, 0, stream>>>(v, fc, vt, flags);
  k_rowstat<<<4096, 256, 0, stream>>>(mask, e, scale, flags);
  k_pvf    <<<512,  256, 0, stream>>>(d_out, vt, q, gam, bet, mask, e, scale, flags);
}